// Round 6
// baseline (555.109 us; speedup 1.0000x reference)
//
#include <hip/hip_runtime.h>
#include <cstdint>

typedef unsigned short u16;
typedef __attribute__((ext_vector_type(8))) short s16x8;   // 8 bf16 (4 VGPRs)
typedef __attribute__((ext_vector_type(4))) float f32x4;

__device__ __forceinline__ u16 f2bf(float f) {
  unsigned int u = __float_as_uint(f);
  return (u16)((u + 0x7FFFu + ((u >> 16) & 1u)) >> 16);   // RNE
}
__device__ __forceinline__ float bf2f(u16 b) {
  return __uint_as_float(((unsigned int)b) << 16);
}
__device__ __forceinline__ f32x4 mfma16(s16x8 a, s16x8 b, f32x4 c) {
  return __builtin_amdgcn_mfma_f32_16x16x32_bf16(a, b, c, 0, 0, 0);
}
__device__ __forceinline__ void gload16(const void* g, void* l) {
  __builtin_amdgcn_global_load_lds((const __attribute__((address_space(1))) void*)g,
                                   (__attribute__((address_space(3))) void*)l, 16, 0, 0);
}

// ---------- weight transpose+cast pair: f32 [K][N] -> bf16 [N][K], z selects ----------
__global__ __launch_bounds__(256) void k_wt(const float* __restrict__ in0, u16* __restrict__ out0,
                                            const float* __restrict__ in1, u16* __restrict__ out1,
                                            int K, int N) {
  const float* in = blockIdx.z ? in1 : in0;
  u16* out = blockIdx.z ? out1 : out0;
  __shared__ float tile[32][33];
  int n0 = blockIdx.x * 32, k0 = blockIdx.y * 32;
  int tx = threadIdx.x & 31, ty = threadIdx.x >> 5;
#pragma unroll
  for (int i = 0; i < 32; i += 8)
    tile[ty + i][tx] = in[(size_t)(k0 + ty + i) * N + n0 + tx];
  __syncthreads();
#pragma unroll
  for (int i = 0; i < 32; i += 8)
    out[(size_t)(n0 + ty + i) * K + k0 + tx] = f2bf(tile[tx][ty + i]);
}

// ---------- fused relu-cast + masked-sum: grid (32b, 8=dc*2+mod, 8 nsplit) ----------
__global__ __launch_bounds__(256) void k_prep(const float* __restrict__ v,
                                              const float* __restrict__ q,
                                              const float* __restrict__ vm,
                                              const float* __restrict__ qm,
                                              u16* __restrict__ rbf,
                                              float* __restrict__ raw,
                                              float* __restrict__ msum) {
  int b = blockIdx.x;
  int mod = blockIdx.y & 1, dc = blockIdx.y >> 1;
  int ns = blockIdx.z;
  const float* x = mod ? q : v;
  const float* mk = (mod ? qm : vm) + b * 256;
  int d = dc * 256 + threadIdx.x;
  const float* xb = x + ((size_t)b * 256 + ns * 32) * 1024 + d;
  u16* ob = rbf + ((size_t)(mod * 8192 + b * 256 + ns * 32)) * 1024 + d;
  float s = 0.f;
#pragma unroll 4
  for (int n = 0; n < 32; ++n) {
    float xv = xb[(size_t)n * 1024];
    s = fmaf(xv, mk[ns * 32 + n], s);
    ob[(size_t)n * 1024] = f2bf(xv > 0.f ? xv : 0.f);
  }
  atomicAdd(&raw[(mod * 32 + b) * 1024 + d], s);
  if (threadIdx.x == 0 && dc == 0) {
    float t = 0.f;
    for (int n = 0; n < 32; ++n) t += mk[ns * 32 + n];
    atomicAdd(&msum[mod * 32 + b], t);
  }
}

// ---------- gates: gs = 1 + sigmoid(relu(mean) @ W + b), grid (4, 32, 2) ----------
__global__ __launch_bounds__(256) void k_gate(const float* __restrict__ raw,
                                              const float* __restrict__ msum,
                                              const float* __restrict__ Wq4v,
                                              const float* __restrict__ bq4v,
                                              const float* __restrict__ Wv4q,
                                              const float* __restrict__ bv4q,
                                              float* __restrict__ gsv,
                                              float* __restrict__ gsq) {
  int b = blockIdx.y, z = blockIdx.z;
  int srcmod = z == 0 ? 1 : 0;   // gs_v <- q-mean, gs_q <- v-mean (cross-wired)
  const float* W = z == 0 ? Wq4v : Wv4q;
  const float* bias = z == 0 ? bq4v : bv4q;
  float* gs = z == 0 ? gsv : gsq;
  const float* r = raw + (srcmod * 32 + b) * 1024;
  float inv = 1.f / msum[srcmod * 32 + b];
  int d = blockIdx.x * 256 + threadIdx.x;
  float acc = bias[d];
#pragma unroll 8
  for (int k = 0; k < 1024; ++k) {
    float m = r[k] * inv;
    m = m > 0.f ? m : 0.f;
    acc = fmaf(m, W[(size_t)k * 1024 + d], acc);
  }
  gs[b * 1024 + d] = 1.f + 1.f / (1.f + expf(-acc));
}

// ================= 128x128 MFMA GEMM, high-occupancy (m97/m103 structure) =================
// A stacked v|q [16384][1024] bf16; BT per-half [N][1024]. 256 thr = 4 waves (2x2),
// per-wave C = 64x64 (acc[4][4] = 64 regs). LDS 32KB = 2 dbuf x (A 8KB + B 8KB),
// 64B rows, XOR swizzle c ^= ((r>>1)&3)<<4 (verified conflict-free R5).
// ~5 blocks/CU resident: per-iter vmcnt(0) drain is covered by other blocks' MFMA
// (m114 overlap) instead of intra-block pipelining. Per K-step(32): 4 gload_lds,
// 8 ds_read_b128, 16 MFMA, 1 barrier.
// EPI 0: bf16 trans out (*mask row, *gs n<2048). EPI 1: f32 out ld=1024.
template <int EPI>
__global__ __launch_bounds__(256, 4) void k_mm(const u16* __restrict__ A,
                                               const u16* __restrict__ BTv,
                                               const u16* __restrict__ BTq,
                                               const float* __restrict__ biasv,
                                               const float* __restrict__ biasq,
                                               u16* __restrict__ outv_b,
                                               u16* __restrict__ outq_b,
                                               float* __restrict__ outf,
                                               const float* __restrict__ maskv,
                                               const float* __restrict__ maskq,
                                               const float* __restrict__ gsv,
                                               const float* __restrict__ gsq) {
  __shared__ __align__(16) u16 lA[2][4096];   // 8KB: [128 rows][32 k]
  __shared__ __align__(16) u16 lB[2][4096];
  int nwg = gridDim.x, cpx = nwg >> 3, bid = blockIdx.x;
  int id = (bid & 7) * cpx + (bid >> 3);     // XCD-contiguous chunks
  int by = id & 127, bx = id >> 7;           // column-major: by fastest (B L2-resident)
  int m0 = by * 128, n0 = bx * 128;
  int half = (m0 >= 8192);
  const u16* BT = half ? BTq : BTv;

  int tid = threadIdx.x, w = tid >> 6, lane = tid & 63;
  int wr = w >> 1, wc = w & 1;
  int la = lane & 15, lb = lane >> 4;

  // staging sources (2 loads/thread per matrix); LDS byte o holds global
  // (row(o), col(o) ^ swz(row)) so swizzled ds_reads see linear data
  int o0 = tid * 16, o1 = 4096 + tid * 16;
  int r0 = o0 >> 6, c0 = o0 & 63;
  int r1 = o1 >> 6, c1 = o1 & 63;
  const char* sA0 = (const char*)A + (size_t)(m0 + r0) * 2048 + (c0 ^ (((r0 >> 1) & 3) << 4));
  const char* sA1 = (const char*)A + (size_t)(m0 + r1) * 2048 + (c1 ^ (((r1 >> 1) & 3) << 4));
  const char* sB0 = (const char*)BT + (size_t)(n0 + r0) * 2048 + (c0 ^ (((r0 >> 1) & 3) << 4));
  const char* sB1 = (const char*)BT + (size_t)(n0 + r1) * 2048 + (c1 ^ (((r1 >> 1) & 3) << 4));

  int aoffs[4], boffs[4];
#pragma unroll
  for (int i = 0; i < 4; ++i) {
    int r = wr * 64 + i * 16 + la;
    aoffs[i] = r * 64 + ((lb * 16) ^ (((r >> 1) & 3) << 4));
  }
#pragma unroll
  for (int j = 0; j < 4; ++j) {
    int r = wc * 64 + j * 16 + la;
    boffs[j] = r * 64 + ((lb * 16) ^ (((r >> 1) & 3) << 4));
  }

  f32x4 acc[4][4] = {};

  // prologue: stage K-step 0
  gload16(sA0, (char*)&lA[0][0] + o0);
  gload16(sA1, (char*)&lA[0][0] + o1);
  gload16(sB0, (char*)&lB[0][0] + o0);
  gload16(sB1, (char*)&lB[0][0] + o1);
  asm volatile("s_waitcnt vmcnt(0)" ::: "memory");
  __builtin_amdgcn_s_barrier();

#pragma unroll 1
  for (int t = 0; t < 32; ++t) {
    int cur = t & 1, nxt = cur ^ 1;
    if (t + 1 < 32) {       // stage next K-step (buffer last read at iter t-1)
      int go = (t + 1) * 64;
      gload16(sA0 + go, (char*)&lA[nxt][0] + o0);
      gload16(sA1 + go, (char*)&lA[nxt][0] + o1);
      gload16(sB0 + go, (char*)&lB[nxt][0] + o0);
      gload16(sB1 + go, (char*)&lB[nxt][0] + o1);
    }
    s16x8 a[4], b[4];
#pragma unroll
    for (int i = 0; i < 4; ++i)
      a[i] = *(const s16x8*)((const char*)&lA[cur][0] + aoffs[i]);
#pragma unroll
    for (int j = 0; j < 4; ++j)
      b[j] = *(const s16x8*)((const char*)&lB[cur][0] + boffs[j]);
    asm volatile("s_waitcnt lgkmcnt(0)" ::: "memory");
    __builtin_amdgcn_sched_barrier(0);
    __builtin_amdgcn_s_setprio(1);
#pragma unroll
    for (int i = 0; i < 4; ++i)
#pragma unroll
      for (int j = 0; j < 4; ++j)
        acc[i][j] = mfma16(a[i], b[j], acc[i][j]);
    __builtin_amdgcn_s_setprio(0);
    asm volatile("s_waitcnt vmcnt(0)" ::: "memory");   // next buffer landed
    __builtin_amdgcn_s_barrier();
  }

  // epilogue
  const float* bias = half ? biasq : biasv;
  const float* mask = half ? maskq : maskv;
  const float* gs = half ? gsq : gsv;
#pragma unroll
  for (int i = 0; i < 4; ++i) {
    int mbase = m0 + wr * 64 + i * 16 + lb * 4;
#pragma unroll
    for (int j = 0; j < 4; ++j) {
      int n = n0 + wc * 64 + j * 16 + la;
      float bn = bias[n];
#pragma unroll
      for (int r = 0; r < 4; ++r) {
        int m = mbase + r;
        float val = acc[i][j][r] + bn;
        if (EPI == 0) {
          int mloc = m & 8191;
          val *= mask[mloc];
          if (n < 2048) val *= gs[((mloc >> 8) << 10) + (n & 1023)];
          (half ? outq_b : outv_b)[(size_t)mloc * 3072 + n] = f2bf(val);
        } else {
          outf[(size_t)m * 1024 + n] = val;
        }
      }
    }
  }
}

// ---------- v-third transpose: trans[b][key][2048+d] -> vT[b][d][key] (bf16) ----------
// grid (4 keytile, 16 dtile, 64 = mod*32+b), 64x64 tiles, swizzled LDS.
__global__ __launch_bounds__(256) void k_vtrans(const u16* __restrict__ tr0,
                                                const u16* __restrict__ tr1,
                                                u16* __restrict__ vt0,
                                                u16* __restrict__ vt1) {
  int bz = blockIdx.z;
  int mod = bz >> 5, b = bz & 31;
  const u16* tr = mod ? tr1 : tr0;
  u16* vt = mod ? vt1 : vt0;
  __shared__ u16 tile[64 * 64];   // phys col-oct = key-oct ^ (d>>3)
  int kt = blockIdx.x, dt = blockIdx.y;
  int t = threadIdx.x, tx = t & 7, ty = t >> 3;   // ty 0..31
  const u16* src = tr + (size_t)b * 786432 + 2048 + dt * 64;
#pragma unroll
  for (int i = 0; i < 2; ++i) {
    int key = ty + i * 32;
    s16x8 vv = *(const s16x8*)(src + (size_t)(kt * 64 + key) * 3072 + tx * 8);
    int oct = key >> 3;
#pragma unroll
    for (int j = 0; j < 8; ++j) {
      int d = tx * 8 + j;
      tile[d * 64 + ((oct ^ (d >> 3)) << 3) + (key & 7)] = (u16)vv[j];
    }
  }
  __syncthreads();
  u16* dst = vt + (size_t)b * 262144 + (size_t)dt * 64 * 256 + kt * 64;
#pragma unroll
  for (int i = 0; i < 2; ++i) {
    int d = ty + i * 32;
    s16x8 ov = *(const s16x8*)&tile[d * 64 + ((tx ^ (d >> 3)) << 3)];
    *(s16x8*)(dst + (size_t)d * 256 + tx * 8) = ov;
  }
}

// ---------- fused attention, grid (64 = h*4+qc, 32 b, 2 mod) ----------
__global__ __launch_bounds__(256) void k_attn(const u16* __restrict__ tr0,
                                              const u16* __restrict__ tr1,
                                              const u16* __restrict__ vt0,
                                              const u16* __restrict__ vt1,
                                              const float* __restrict__ mk0,
                                              const float* __restrict__ mk1,
                                              const float* __restrict__ x0,
                                              const float* __restrict__ x1,
                                              u16* __restrict__ ao0,
                                              u16* __restrict__ ao1) {
  int z = blockIdx.z;
  const u16* trans = z ? tr1 : tr0;
  const u16* vt = z ? vt1 : vt0;
  const float* mask = z ? mk1 : mk0;
  const float* xorig = z ? x1 : x0;
  u16* attin = z ? ao1 : ao0;

  __shared__ u16 Kl[16384];     // 32KB: K [256][64] XOR-swizzled; reused as P
  __shared__ u16 Vt[64 * 256];  // 32KB: V^T [d][key], key-oct ^ (d&7) swizzle
  int h = blockIdx.x >> 2, qc = blockIdx.x & 3;
  int b = blockIdx.y;
  int t = threadIdx.x, w = t >> 6, lane = t & 63;
  const u16* tb = trans + (size_t)b * 256 * 3072;
  const char* tbc = (const char*)tb;

  // stage K (k-third cols [0,1024), head slice), 16B-XOR swizzle on 128B rows
#pragma unroll
  for (int i = 0; i < 8; ++i) {
    int o = i * 4096 + t * 16;
    int row = o >> 7, colb = o & 127;
    gload16(tbc + (size_t)row * 6144 + h * 128 + (colb ^ ((row & 7) << 4)),
            (char*)Kl + o);
  }
  // stage V^T from pre-transposed vT, key-oct swizzle
  const char* vtb = (const char*)(vt + (size_t)b * 262144 + (size_t)h * 64 * 256);
#pragma unroll
  for (int i = 0; i < 8; ++i) {
    int o = i * 4096 + t * 16;
    int d = o >> 9, oct = (o >> 4) & 31;
    gload16(vtb + d * 512 + ((oct ^ (d & 7)) << 4), (char*)Vt + o);
  }
  __syncthreads();

  int la = lane & 15, lb = lane >> 4;
  int q0 = qc * 64 + w * 16;
  const u16* qrow = tb + (size_t)(q0 + la) * 3072 + 1024 + h * 64;  // q-third
  s16x8 qf0 = *(const s16x8*)(qrow + lb * 8);
  s16x8 qf1 = *(const s16x8*)(qrow + 32 + lb * 8);

  // QK^T, scores in regs
  f32x4 sc[16];
#pragma unroll
  for (int nt = 0; nt < 16; ++nt) {
    int row = nt * 16 + la;
    int sw = (row & 7) << 4;
    s16x8 kf0 = *(const s16x8*)((const char*)Kl + row * 128 + ((lb * 16) ^ sw));
    s16x8 kf1 = *(const s16x8*)((const char*)Kl + row * 128 + ((64 + lb * 16) ^ sw));
    f32x4 s = {0.f, 0.f, 0.f, 0.f};
    s = mfma16(qf0, kf0, s);
    s = mfma16(qf1, kf1, s);
    sc[nt] = s;
  }
  __syncthreads();   // all waves done with Kl before P overwrites

  u16* Pw = Kl + w * 4096;     // per-wave P [16][256], swizzled
  const float* mb = mask + b * 256;
  float rsum[4] = {0.f, 0.f, 0.f, 0.f};
#pragma unroll
  for (int nt = 0; nt < 16; ++nt) {
    int key = nt * 16 + la;
    float km = mb[key];
    int quad = key >> 3, klow = key & 7;
#pragma unroll
    for (int r = 0; r < 4; ++r) {
      float p = (km != 0.f) ? expf(sc[nt][r] * 0.125f) : 0.f;  // exp(s/sqrt(64))
      u16 pb = f2bf(p);
      int lr = lb * 4 + r;
      rsum[r] += bf2f(pb);
      Pw[lr * 256 + ((quad ^ (lr & 7)) << 3) + klow] = pb;
    }
  }
#pragma unroll
  for (int r = 0; r < 4; ++r) {
    rsum[r] += __shfl_xor(rsum[r], 1);
    rsum[r] += __shfl_xor(rsum[r], 2);
    rsum[r] += __shfl_xor(rsum[r], 4);
    rsum[r] += __shfl_xor(rsum[r], 8);
  }
  __syncthreads();

  f32x4 o[4] = {};
  for (int kt = 0; kt < 8; ++kt) {
    int pq = kt * 4 + lb;
    s16x8 pa = *(const s16x8*)&Pw[la * 256 + ((pq ^ (la & 7)) << 3)];
#pragma unroll
    for (int dt = 0; dt < 4; ++dt) {
      int d = dt * 16 + la;
      s16x8 vb = *(const s16x8*)&Vt[d * 256 + ((pq ^ (d & 7)) << 3)];
      o[dt] = mfma16(pa, vb, o[dt]);
    }
  }

#pragma unroll
  for (int dt = 0; dt < 4; ++dt) {
    int dcol = h * 64 + dt * 16 + la;
#pragma unroll
    for (int r = 0; r < 4; ++r) {
      int qr = q0 + lb * 4 + r;
      size_t gi = ((size_t)b * 256 + qr) * 1024 + dcol;
      attin[gi] = f2bf(xorig[gi] + o[dt][r] / rsum[r]);
    }
  }
}

extern "C" void kernel_launch(void* const* d_in, const int* in_sizes, int n_in,
                              void* d_out, int out_size, void* d_ws, size_t ws_size,
                              hipStream_t stream) {
  const float* v      = (const float*)d_in[0];
  const float* q      = (const float*)d_in[1];
  const float* v_mask = (const float*)d_in[2];
  const float* q_mask = (const float*)d_in[3];
  const float* w_v4q  = (const float*)d_in[4];
  const float* b_v4q  = (const float*)d_in[5];
  const float* w_q4v  = (const float*)d_in[6];
  const float* b_q4v  = (const float*)d_in[7];
  const float* w_vlin = (const float*)d_in[8];
  const float* b_vlin = (const float*)d_in[9];
  const float* w_qlin = (const float*)d_in[10];
  const float* b_qlin = (const float*)d_in[11];
  const float* w_vout = (const float*)d_in[12];
  const float* b_vout = (const float*)d_in[13];
  const float* w_qout = (const float*)d_in[14];
  const float* b_qout = (const float*)d_in[15];
  float* out = (float*)d_out;

  char* ws = (char*)d_ws;
  u16* rbf       = (u16*)(ws);                    // 33.5MB stacked v|q; becomes attin
  u16* rbf_v     = rbf;
  u16* rbf_q     = (u16*)(ws + 16777216);
  u16* woutT_v   = (u16*)(ws + 33554432);         // 2.1MB
  u16* woutT_q   = (u16*)(ws + 35651584);         // 2.1MB
  u16* trans_v   = (u16*)(ws + 37748736);         // 50.3MB
  // overlay region (wlinT/raw/gs dead after k_mm<0>; vT_v reuses it)
  u16* wlinT_v   = (u16*)(ws + 88080384);         // 6.3MB
  u16* wlinT_q   = (u16*)(ws + 94371840);         // 6.3MB
  float* raw     = (float*)(ws + 100663296);      // 2x32x1024 f32 sums
  float* msum    = (float*)(ws + 100925440);      // 2x32 f32
  float* gs_v    = (float*)(ws + 100925696);      // 1+q4v_gate
  float* gs_q    = (float*)(ws + 101056768);      // 1+v4q_gate
  u16* vT_v      = (u16*)(ws + 88080384);         // 16.8MB overlay (after mm0)
  u16* trans_q   = (u16*)d_out;                   // 50.3MB parked in d_out
  u16* vT_q      = (u16*)((char*)d_out + 50331648);  // 16.8MB (total exactly 64MiB)

  dim3 blk(256);
  hipMemsetAsync(raw, 0, 262400, stream);         // raw + msum
  // weights -> bf16 [N][K]
  k_wt<<<dim3(96, 32, 2), blk, 0, stream>>>(w_vlin, wlinT_v, w_qlin, wlinT_q, 1024, 3072);
  k_wt<<<dim3(32, 32, 2), blk, 0, stream>>>(w_vout, woutT_v, w_qout, woutT_q, 1024, 1024);
  // fused relu-cast + masked partial sums
  k_prep<<<dim3(32, 8, 8), blk, 0, stream>>>(v, q, v_mask, q_mask, rbf, raw, msum);
  // gates (cross-wired)
  k_gate<<<dim3(4, 32, 2), blk, 0, stream>>>(raw, msum, w_q4v, b_q4v, w_v4q, b_v4q, gs_v, gs_q);
  // trans = (relu(x) @ Wlin + b) * mask, k/q thirds * (1+gate) — fused v|q
  k_mm<0><<<dim3(3072), blk, 0, stream>>>(rbf, wlinT_v, wlinT_q, b_vlin, b_qlin,
                                          trans_v, trans_q, nullptr,
                                          v_mask, q_mask, gs_v, gs_q);
  // v-third -> vT[b][d][key]
  k_vtrans<<<dim3(4, 16, 64), blk, 0, stream>>>(trans_v, trans_q, vT_v, vT_q);
  // attention (both modalities); writes bf16(x + update) into rbf
  k_attn<<<dim3(64, 32, 2), blk, 0, stream>>>(trans_v, trans_q, vT_v, vT_q,
                                              v_mask, q_mask, v, q, rbf_v, rbf_q);
  // out = attin @ Wout + b — f32, overwrites d_out after attn consumed it
  k_mm<1><<<dim3(1024), blk, 0, stream>>>(rbf, woutT_v, woutT_q, b_vout, b_qout,
                                          nullptr, nullptr, out,
                                          nullptr, nullptr, nullptr, nullptr);
}